// Round 1
// baseline (50.008 us; speedup 1.0000x reference)
//
#include <hip/hip_runtime.h>
#include <math.h>

#define POOLED 7
#define SCALE 0.0625f

__global__ __launch_bounds__(256) void roipool_kernel(
    const float* __restrict__ feat, const float* __restrict__ rois,
    float* __restrict__ out, int C, int H, int W, int total)
{
    int idx = blockIdx.x * blockDim.x + threadIdx.x;
    if (idx >= total) return;

    int pw = idx % POOLED;
    int ph = (idx / POOLED) % POOLED;
    int c  = (idx / (POOLED * POOLED)) % C;
    int n  = idx / (POOLED * POOLED * C);

    const float* r = rois + n * 5;
    int b  = (int)r[0];
    int x1 = (int)(r[1] * SCALE);
    int y1 = (int)(r[2] * SCALE);
    int x2 = (int)(r[3] * SCALE);
    int y2 = (int)(r[4] * SCALE);
    int rh = y2 - y1 + 1;
    int rw = x2 - x1 + 1;

    int hs = y1 + (ph * rh) / POOLED;
    int he = y1 + ((ph + 1) * rh + POOLED - 1) / POOLED;
    int ws = x1 + (pw * rw) / POOLED;
    int we = x1 + ((pw + 1) * rw + POOLED - 1) / POOLED;

    const float* plane = feat + ((size_t)b * C + c) * (size_t)(H * W);
    float m = -INFINITY;
    for (int h = hs; h < he; ++h) {
        const float* row = plane + min(h, H - 1) * W;
        for (int w = ws; w < we; ++w) {
            m = fmaxf(m, row[min(w, W - 1)]);
        }
    }
    out[idx] = m;
}

extern "C" void kernel_launch(void* const* d_in, const int* in_sizes, int n_in,
                              void* d_out, int out_size, void* d_ws, size_t ws_size,
                              hipStream_t stream) {
    const float* feat = (const float*)d_in[0];
    const float* rois = (const float*)d_in[1];
    float* out = (float*)d_out;

    const int C = 256, H = 56, W = 56;
    int N = in_sizes[1] / 5;
    int total = N * C * POOLED * POOLED;   // == out_size

    int threads = 256;
    int blocks = (total + threads - 1) / threads;
    roipool_kernel<<<blocks, threads, 0, stream>>>(feat, rois, out, C, H, W, total);
}